// Round 17
// baseline (49.148 us; speedup 1.0000x reference)
//
#include <hip/hip_runtime.h>
#include <hip/hip_bf16.h>

#define NT 256

// distance magnitude part: (1 - exp/16) * norm, exp = bit_length(xor+1)
__device__ __forceinline__ float dist_mag(int mag, int pos, float norm) {
    int x = (mag ^ pos) + 1;                      // in [1, 65536]
    float s = (float)(32 - __clz(x)) * 0.0625f;   // exp/16, exact
    return (1.0f - s) * norm;                     // one rounding on *norm
}

__global__ __launch_bounds__(NT)
void cg_kernel(const int* __restrict__ sta_loc,
               const int* __restrict__ pos_loc,
               const float* __restrict__ eu_val,
               const float* __restrict__ eu_norm,
               const int* __restrict__ rnd,
               const float* __restrict__ rand_vals,
               const float* __restrict__ t_rand,
               float* __restrict__ out)          // r16: d_out is FLOAT32 (2816 floats)
{
#pragma clang fp contract(off)
    const int t = blockIdx.x;
    const int tid = threadIdx.x;

    __shared__ int   sh_pos[128][8];
    __shared__ float sh_a[128][8];     // (csp_sum - cos)/8
    __shared__ float sh_cos[128][8];   // cos_sta_pos
    __shared__ float sh_euv[128];
    __shared__ float sh_eun[128];
    __shared__ int   sh_sta[8];
    __shared__ int   sh_rnd[16][4][8];
    __shared__ float sh_lcos[129][8];
    __shared__ float sh_lcro[129][8];
    __shared__ float sh_p64[32][8];    // partials for c=64 column
    __shared__ int   sh_amin[8];
    __shared__ int   sh_ci[8];
    __shared__ float sh_selc[8], sh_selr[8];

    // ---- Phase A: stage row t into LDS (inputs are int32, verified r9) ----
    for (int i = tid; i < 1024; i += NT) ((int*)sh_pos)[i] = pos_loc[t*1024 + i];
    for (int i = tid; i < 512; i += NT)  ((int*)sh_rnd)[i] = rnd[t*512 + i];
    if (tid < 128) { sh_euv[tid] = eu_val[t*128 + tid]; sh_eun[tid] = eu_norm[t*128 + tid]; }
    if (tid >= 128 && tid < 136) sh_sta[tid - 128] = sta_loc[t*8 + (tid - 128)];
    __syncthreads();

    // ---- Phase B: cos_sta_pos, csp_sum, a = (csp - cos)/8 ----
    for (int i = tid; i < 1024; i += NT) {
        int s = i >> 3, p = i & 7;
        sh_cos[s][p] = dist_mag(sh_sta[p], sh_pos[s][p], sh_eun[s]);
    }
    __syncthreads();
    if (tid < 128) {
        float csp = 0.0f;
        for (int p = 0; p < 8; ++p) csp += sh_cos[tid][p];
        for (int p = 0; p < 8; ++p) sh_a[tid][p] = (csp - sh_cos[tid][p]) * 0.125f;
    }
    __syncthreads();

    const float HI = 1.0f - 1e-6f;

    // ---- Phase C: p = tid&7, jb = tid>>3 in [0,32); columns j and j+32 ----
    // Negative half c=j+65 has same magnitude, dist = -dist -> computed in same pass.
    {
        const int p = tid & 7, jb = tid >> 3;
        for (int jj = 0; jj < 2; ++jj) {
            const int j = jb + jj * 32;
            const int h = j >> 2, k = j & 3;
            const int mag = (sh_sta[p] ^ (1 << h)) ^ (sh_rnd[h][k][p] & ((1 << h) - 1));
            const float sneg = (mag == 0) ? 1.0f : -1.0f;

            float accP = 0.0f, accN = 0.0f;
            for (int s = 0; s < 96; ++s) {
                float d  = dist_mag(mag, sh_pos[s][p], sh_eun[s]);
                float a  = sh_a[s][p];
                float ev = sh_euv[s];
                float ctp = a + d * 0.125f;
                float ctn = a + (sneg * d) * 0.125f;
                float e1 = ctp - ev, e2 = ctn - ev;
                accP += e1 * e1;
                accN += e2 * e2;
            }
            float bceP = 0.0f, bceN = 0.0f;
            for (int s = 96; s < 128; ++s) {
                float d  = dist_mag(mag, sh_pos[s][p], sh_eun[s]);
                float a  = sh_a[s][p];
                float ev = sh_euv[s];
                float ctp = a + d * 0.125f;
                float ctn = a + (sneg * d) * 0.125f;
                float pp = fminf(fmaxf((ctp + 1.0f) * 0.5f, 1e-6f), HI);
                float pn = fminf(fmaxf((ctn + 1.0f) * 0.5f, 1e-6f), HI);
                bceP -= ev * logf(pp) + (1.0f - ev) * log1pf(-pp);
                bceN -= ev * logf(pn) + (1.0f - ev) * log1pf(-pn);
            }
            sh_lcos[j][p]      = accP / 96.0f;
            sh_lcos[j + 65][p] = accN / 96.0f;
            sh_lcro[j][p]      = bceP / 32.0f;
            sh_lcro[j + 65][p] = bceN / 32.0f;
        }
    }

    // ---- Phase C2: column c=64 (dist == cos_sta_pos), 4 s-values/thread ----
    {
        const int p = tid & 7, strip = tid >> 3;   // strip in [0,32)
        float acc = 0.0f;
        for (int ss = 0; ss < 4; ++ss) {
            int s = strip * 4 + ss;
            float d  = sh_cos[s][p];
            float a  = sh_a[s][p];
            float ev = sh_euv[s];
            float ct = a + d * 0.125f;
            if (s < 96) { float e = ct - ev; acc += e * e; }
            else {
                float pc = fminf(fmaxf((ct + 1.0f) * 0.5f, 1e-6f), HI);
                acc -= ev * logf(pc) + (1.0f - ev) * log1pf(-pc);
            }
        }
        sh_p64[strip][p] = acc;   // strips 0..23 pure SE, 24..31 pure BCE
    }
    __syncthreads();
    if (tid < 8) {
        float c0 = 0.0f, c1 = 0.0f;
        for (int q = 0; q < 24; ++q)  c0 += sh_p64[q][tid];
        for (int q = 24; q < 32; ++q) c1 += sh_p64[q][tid];
        sh_lcos[64][tid] = c0 / 96.0f;
        sh_lcro[64][tid] = c1 / 32.0f;
    }
    __syncthreads();

    // ---- Phase D: per-p argmin over c (first-min like np.argmin) ----
    if (tid < 8) {
        const int p = tid;
        float best = sh_lcos[0][p] + sh_lcro[0][p];
        int bi = 0;
        for (int c = 1; c < 129; ++c) {
            float v = sh_lcos[c][p] + sh_lcro[c][p];
            if (v < best) { best = v; bi = c; }
        }
        sh_amin[p] = bi;
    }
    __syncthreads();

    // ---- Phase E: 4 smallest rand_vals (stable) -> cnc_indices ----
    if (tid == 0) {
        float rv[8];
        for (int p = 0; p < 8; ++p) rv[p] = rand_vals[t*8 + p];
        const bool tm = t_rand[t] < 0.5f;
        int ci[8];
        bool used[8];
        for (int p = 0; p < 8; ++p) { ci[p] = 64; used[p] = false; }
        for (int jj = 0; jj < 4; ++jj) {
            int bi = -1; float bv = 0.0f;
            for (int p = 0; p < 8; ++p)
                if (!used[p] && (bi < 0 || rv[p] < bv)) { bv = rv[p]; bi = p; }
            used[bi] = true;
            ci[bi] = tm ? sh_amin[bi] : 64;
        }
        for (int p = 0; p < 8; ++p) sh_ci[p] = ci[p];
    }
    __syncthreads();

    // ---- Phase F: gather selected locs + losses; write FLOAT32 out ----
    if (tid < 8) {
        const int p = tid;
        const int idx = sh_ci[p];
        int v;
        if (idx == 64) v = sh_sta[p];
        else {
            int j = (idx < 64) ? idx : (idx - 65);
            int h = j >> 2, k = j & 3;
            int mag = (sh_sta[p] ^ (1 << h)) ^ (sh_rnd[h][k][p] & ((1 << h) - 1));
            v = (idx < 64) ? mag : -mag;
        }
        out[t*8 + p] = (float)v;                  // exact: |v| < 2^16
        sh_selc[p] = sh_lcos[idx][p];
        sh_selr[p] = sh_lcro[idx][p];
    }
    __syncthreads();
    if (tid == 0) {
        float sc = 0.0f, sr = 0.0f, stt = 0.0f;
        for (int p = 0; p < 8; ++p) {
            sc += sh_selc[p];
            sr += sh_selr[p];
            stt += sh_selc[p] + sh_selr[p];
        }
        out[2048 + t]       = sc * 0.125f;        // real_loss_cos
        out[2048 + 256 + t] = sr * 0.125f;        // real_loss_cro
        out[2048 + 512 + t] = stt * 0.125f;       // real_loss_tot
    }
}

extern "C" __attribute__((visibility("default")))
void kernel_launch(void* const* d_in, const int* in_sizes, int n_in,
                   void* d_out, int out_size, void* d_ws, size_t ws_size,
                   hipStream_t stream) {
    const int*   sta = (const int*)d_in[0];
    const int*   pos = (const int*)d_in[1];
    const float* euv = (const float*)d_in[2];
    const float* eun = (const float*)d_in[3];
    // d_in[4] = mask: all ones by construction (lth_cos=96, lth_cro=32 hardcoded)
    const int*   rnd = (const int*)d_in[5];
    const float* rv  = (const float*)d_in[6];
    const float* tr  = (const float*)d_in[7];
    cg_kernel<<<256, NT, 0, stream>>>(sta, pos, euv, eun, rnd, rv, tr, (float*)d_out);
}

// Round 18
// 43.337 us; speedup vs baseline: 1.1341x; 1.1341x over previous
//
#include <hip/hip_runtime.h>

#define NT 512

// distance magnitude part: (1 - exp/16) * norm, exp = bit_length(xor+1)
__device__ __forceinline__ float dist_mag(int mag, int pos, float norm) {
    int x = (mag ^ pos) + 1;                      // in [1, 65536]
    float s = (float)(32 - __clz(x)) * 0.0625f;   // exp/16, exact
    return (1.0f - s) * norm;                     // one rounding on *norm
}

__global__ __launch_bounds__(NT)
void cg_kernel(const int* __restrict__ sta_loc,
               const int* __restrict__ pos_loc,
               const float* __restrict__ eu_val,
               const float* __restrict__ eu_norm,
               const int* __restrict__ rnd,
               const float* __restrict__ rand_vals,
               const float* __restrict__ t_rand,
               float* __restrict__ out)          // d_out is FLOAT32 (2816 floats)
{
#pragma clang fp contract(off)
    const int t = blockIdx.x;
    const int tid = threadIdx.x;

    __shared__ int   sh_pos[128][8];
    __shared__ float sh_a[128][8];     // (csp_sum - cos)/8
    __shared__ float sh_cos[128][8];   // cos_sta_pos
    __shared__ float sh_euv[128];
    __shared__ float sh_eun[128];
    __shared__ int   sh_sta[8];
    __shared__ int   sh_rnd[16][4][8];
    __shared__ float sh_lcos[129][8];
    __shared__ float sh_lcro[129][8];
    __shared__ float sh_p64[64][8];    // partials for c=64 column
    __shared__ int   sh_amin[8];
    __shared__ int   sh_ci[8];
    __shared__ float sh_selc[8], sh_selr[8];

    // ---- Phase A: stage row t into LDS (inputs are int32, verified r9) ----
    for (int i = tid; i < 1024; i += NT) ((int*)sh_pos)[i] = pos_loc[t*1024 + i];
    for (int i = tid; i < 512; i += NT)  ((int*)sh_rnd)[i] = rnd[t*512 + i];
    if (tid < 128) { sh_euv[tid] = eu_val[t*128 + tid]; sh_eun[tid] = eu_norm[t*128 + tid]; }
    if (tid >= 128 && tid < 136) sh_sta[tid - 128] = sta_loc[t*8 + (tid - 128)];
    __syncthreads();

    // ---- Phase B: cos_sta_pos, csp_sum, a = (csp - cos)/8 ----
    for (int i = tid; i < 1024; i += NT) {
        int s = i >> 3, p = i & 7;
        sh_cos[s][p] = dist_mag(sh_sta[p], sh_pos[s][p], sh_eun[s]);
    }
    __syncthreads();
    if (tid < 128) {
        float csp = 0.0f;
        for (int p = 0; p < 8; ++p) csp += sh_cos[tid][p];
        for (int p = 0; p < 8; ++p) sh_a[tid][p] = (csp - sh_cos[tid][p]) * 0.125f;
    }
    __syncthreads();

    const float HI = 1.0f - 1e-6f;

    // ---- Phase C: one thread per (j,p), j in [0,64): columns c=j and c=j+65 ----
    // Negative half c=j+65 has same magnitude; dist = -dist -> same pass.
    {
        const int p = tid & 7, j = tid >> 3;
        const int h = j >> 2, k = j & 3;
        const int mag = (sh_sta[p] ^ (1 << h)) ^ (sh_rnd[h][k][p] & ((1 << h) - 1));
        const float sneg = (mag == 0) ? 1.0f : -1.0f;

        float accP = 0.0f, accN = 0.0f;
        for (int s = 0; s < 96; ++s) {
            float d  = dist_mag(mag, sh_pos[s][p], sh_eun[s]);
            float a  = sh_a[s][p];
            float ev = sh_euv[s];
            float ctp = a + d * 0.125f;
            float ctn = a + (sneg * d) * 0.125f;
            float e1 = ctp - ev, e2 = ctn - ev;
            accP += e1 * e1;
            accN += e2 * e2;
        }
        float bceP = 0.0f, bceN = 0.0f;
        for (int s = 96; s < 128; ++s) {
            float d  = dist_mag(mag, sh_pos[s][p], sh_eun[s]);
            float a  = sh_a[s][p];
            float ev = sh_euv[s];
            float ctp = a + d * 0.125f;
            float ctn = a + (sneg * d) * 0.125f;
            float pp = fminf(fmaxf((ctp + 1.0f) * 0.5f, 1e-6f), HI);
            float pn = fminf(fmaxf((ctn + 1.0f) * 0.5f, 1e-6f), HI);
            bceP -= ev * logf(pp) + (1.0f - ev) * log1pf(-pp);
            bceN -= ev * logf(pn) + (1.0f - ev) * log1pf(-pn);
        }
        sh_lcos[j][p]      = accP / 96.0f;
        sh_lcos[j + 65][p] = accN / 96.0f;
        sh_lcro[j][p]      = bceP / 32.0f;
        sh_lcro[j + 65][p] = bceN / 32.0f;
    }

    // ---- Phase C2: column c=64 (dist == cos_sta_pos), 2 s-values/thread ----
    {
        const int p = tid & 7, strip = tid >> 3;   // strip in [0,64)
        float acc = 0.0f;
        for (int ss = 0; ss < 2; ++ss) {
            int s = strip * 2 + ss;
            float d  = sh_cos[s][p];
            float a  = sh_a[s][p];
            float ev = sh_euv[s];
            float ct = a + d * 0.125f;
            if (s < 96) { float e = ct - ev; acc += e * e; }
            else {
                float pc = fminf(fmaxf((ct + 1.0f) * 0.5f, 1e-6f), HI);
                acc -= ev * logf(pc) + (1.0f - ev) * log1pf(-pc);
            }
        }
        sh_p64[strip][p] = acc;   // strips 0..47 pure SE, 48..63 pure BCE
    }
    __syncthreads();
    if (tid < 8) {
        float c0 = 0.0f, c1 = 0.0f;
        for (int q = 0; q < 48; ++q)  c0 += sh_p64[q][tid];
        for (int q = 48; q < 64; ++q) c1 += sh_p64[q][tid];
        sh_lcos[64][tid] = c0 / 96.0f;
        sh_lcro[64][tid] = c1 / 32.0f;
    }
    __syncthreads();

    // ---- Phase D: per-p argmin over c (first-min like np.argmin) ----
    if (tid < 8) {
        const int p = tid;
        float best = sh_lcos[0][p] + sh_lcro[0][p];
        int bi = 0;
        for (int c = 1; c < 129; ++c) {
            float v = sh_lcos[c][p] + sh_lcro[c][p];
            if (v < best) { best = v; bi = c; }
        }
        sh_amin[p] = bi;
    }
    __syncthreads();

    // ---- Phase E: 4 smallest rand_vals (stable) -> cnc_indices ----
    if (tid == 0) {
        float rv[8];
        for (int p = 0; p < 8; ++p) rv[p] = rand_vals[t*8 + p];
        const bool tm = t_rand[t] < 0.5f;
        int ci[8];
        bool used[8];
        for (int p = 0; p < 8; ++p) { ci[p] = 64; used[p] = false; }
        for (int jj = 0; jj < 4; ++jj) {
            int bi = -1; float bv = 0.0f;
            for (int p = 0; p < 8; ++p)
                if (!used[p] && (bi < 0 || rv[p] < bv)) { bv = rv[p]; bi = p; }
            used[bi] = true;
            ci[bi] = tm ? sh_amin[bi] : 64;
        }
        for (int p = 0; p < 8; ++p) sh_ci[p] = ci[p];
    }
    __syncthreads();

    // ---- Phase F: gather selected locs + losses; write FLOAT32 out ----
    if (tid < 8) {
        const int p = tid;
        const int idx = sh_ci[p];
        int v;
        if (idx == 64) v = sh_sta[p];
        else {
            int j = (idx < 64) ? idx : (idx - 65);
            int h = j >> 2, k = j & 3;
            int mag = (sh_sta[p] ^ (1 << h)) ^ (sh_rnd[h][k][p] & ((1 << h) - 1));
            v = (idx < 64) ? mag : -mag;
        }
        out[t*8 + p] = (float)v;                  // exact: |v| < 2^16
        sh_selc[p] = sh_lcos[idx][p];
        sh_selr[p] = sh_lcro[idx][p];
    }
    __syncthreads();
    if (tid == 0) {
        float sc = 0.0f, sr = 0.0f, stt = 0.0f;
        for (int p = 0; p < 8; ++p) {
            sc += sh_selc[p];
            sr += sh_selr[p];
            stt += sh_selc[p] + sh_selr[p];
        }
        out[2048 + t]       = sc * 0.125f;        // real_loss_cos
        out[2048 + 256 + t] = sr * 0.125f;        // real_loss_cro
        out[2048 + 512 + t] = stt * 0.125f;       // real_loss_tot
    }
}

extern "C" __attribute__((visibility("default")))
void kernel_launch(void* const* d_in, const int* in_sizes, int n_in,
                   void* d_out, int out_size, void* d_ws, size_t ws_size,
                   hipStream_t stream) {
    const int*   sta = (const int*)d_in[0];
    const int*   pos = (const int*)d_in[1];
    const float* euv = (const float*)d_in[2];
    const float* eun = (const float*)d_in[3];
    // d_in[4] = mask: all ones by construction (lth_cos=96, lth_cro=32 hardcoded)
    const int*   rnd = (const int*)d_in[5];
    const float* rv  = (const float*)d_in[6];
    const float* tr  = (const float*)d_in[7];
    cg_kernel<<<256, NT, 0, stream>>>(sta, pos, euv, eun, rnd, rv, tr, (float*)d_out);
}

// Round 19
// 29.190 us; speedup vs baseline: 1.6837x; 1.4846x over previous
//
#include <hip/hip_runtime.h>

#define NT 512

// distance magnitude part: (1 - exp/16) * norm, exp = bit_length(xor+1)
__device__ __forceinline__ float dist_mag(int mag, int pos, float norm) {
    int x = (mag ^ pos) + 1;                      // in [1, 65536]
    float s = (float)(32 - __clz(x)) * 0.0625f;   // exp/16, exact
    return (1.0f - s) * norm;                     // one rounding on *norm
}

__global__ __launch_bounds__(NT)
void cg_kernel(const int* __restrict__ sta_loc,
               const int* __restrict__ pos_loc,
               const float* __restrict__ eu_val,
               const float* __restrict__ eu_norm,
               const int* __restrict__ rnd,
               const float* __restrict__ rand_vals,
               const float* __restrict__ t_rand,
               float* __restrict__ out)          // d_out is FLOAT32 (2816 floats)
{
#pragma clang fp contract(off)
    const int t = blockIdx.x;
    const int tid = threadIdx.x;

    __shared__ int   sh_pos[128][8];
    __shared__ float sh_a[128][8];     // (csp_sum - cos)/8
    __shared__ float sh_cos[128][8];   // cos_sta_pos
    __shared__ float sh_euv[128];
    __shared__ float sh_eun[128];
    __shared__ int   sh_sta[8];
    __shared__ int   sh_rnd[16][4][8];
    __shared__ float sh_lcos[129][8];
    __shared__ float sh_lcro[129][8];
    __shared__ float sh_p64[64][8];    // partials for c=64 column
    __shared__ int   sh_amin[8];
    __shared__ int   sh_ci[8];
    __shared__ float sh_selc[8], sh_selr[8];
    // BCE term table: [sign][e-1][s-96 (padded 33)][p]. Entry = exact same
    // float expression as the inline BCE term -> bit-identical accumulation.
    __shared__ float sh_tbl[2][17][33][8];

    // ---- Phase A: stage row t into LDS (inputs are int32, verified r9) ----
    for (int i = tid; i < 1024; i += NT) ((int*)sh_pos)[i] = pos_loc[t*1024 + i];
    for (int i = tid; i < 512; i += NT)  ((int*)sh_rnd)[i] = rnd[t*512 + i];
    if (tid < 128) { sh_euv[tid] = eu_val[t*128 + tid]; sh_eun[tid] = eu_norm[t*128 + tid]; }
    if (tid >= 128 && tid < 136) sh_sta[tid - 128] = sta_loc[t*8 + (tid - 128)];
    __syncthreads();

    // ---- Phase B: cos_sta_pos, csp_sum, a = (csp - cos)/8 ----
    for (int i = tid; i < 1024; i += NT) {
        int s = i >> 3, p = i & 7;
        sh_cos[s][p] = dist_mag(sh_sta[p], sh_pos[s][p], sh_eun[s]);
    }
    __syncthreads();
    if (tid < 128) {
        float csp = 0.0f;
        for (int p = 0; p < 8; ++p) csp += sh_cos[tid][p];
        for (int p = 0; p < 8; ++p) sh_a[tid][p] = (csp - sh_cos[tid][p]) * 0.125f;
    }
    __syncthreads();

    const float HI = 1.0f - 1e-6f;

    // ---- Phase B2: build BCE table (17 entries/thread, 2 accurate logs each) ----
    for (int i = tid; i < 2 * 17 * 32 * 8; i += NT) {
        int p    = i & 7;
        int sp   = (i >> 3) & 31;
        int r    = i >> 8;              // 0..33
        int sign = (r >= 17) ? 1 : 0;
        int e    = r - sign * 17 + 1;   // 1..17
        int s    = 96 + sp;
        float norm = sh_eun[s];
        float a    = sh_a[s][p];
        float ev   = sh_euv[s];
        float d  = (1.0f - (float)e * 0.0625f) * norm;   // == dist_mag rounding
        float dd = sign ? -d : d;                        // exact sign flip
        float ct = a + dd * 0.125f;
        float pc = fminf(fmaxf((ct + 1.0f) * 0.5f, 1e-6f), HI);
        sh_tbl[sign][e - 1][sp][p] = ev * logf(pc) + (1.0f - ev) * log1pf(-pc);
    }
    __syncthreads();

    // ---- Phase C: one thread per (j,p), j in [0,64): columns c=j and c=j+65 ----
    {
        const int p = tid & 7, j = tid >> 3;
        const int h = j >> 2, k = j & 3;
        const int mag = (sh_sta[p] ^ (1 << h)) ^ (sh_rnd[h][k][p] & ((1 << h) - 1));
        const float sneg = (mag == 0) ? 1.0f : -1.0f;
        const int signSel = (mag == 0) ? 0 : 1;   // mag==0: neg column == pos column

        float accP = 0.0f, accN = 0.0f;
        for (int s = 0; s < 96; ++s) {
            float d  = dist_mag(mag, sh_pos[s][p], sh_eun[s]);
            float a  = sh_a[s][p];
            float ev = sh_euv[s];
            float ctp = a + d * 0.125f;
            float ctn = a + (sneg * d) * 0.125f;
            float e1 = ctp - ev, e2 = ctn - ev;
            accP += e1 * e1;
            accN += e2 * e2;
        }
        float bceP = 0.0f, bceN = 0.0f;
        for (int sp = 0; sp < 32; ++sp) {
            int x  = (mag ^ sh_pos[96 + sp][p]) + 1;
            int e0 = 31 - __clz(x);                 // e-1
            bceP -= sh_tbl[0][e0][sp][p];
            bceN -= sh_tbl[signSel][e0][sp][p];
        }
        sh_lcos[j][p]      = accP / 96.0f;
        sh_lcos[j + 65][p] = accN / 96.0f;
        sh_lcro[j][p]      = bceP / 32.0f;
        sh_lcro[j + 65][p] = bceN / 32.0f;
    }

    // ---- Phase C2: column c=64 (dist == cos_sta_pos), 2 s-values/thread ----
    {
        const int p = tid & 7, strip = tid >> 3;   // strip in [0,64)
        float acc = 0.0f;
        for (int ss = 0; ss < 2; ++ss) {
            int s = strip * 2 + ss;
            float d  = sh_cos[s][p];
            float a  = sh_a[s][p];
            float ev = sh_euv[s];
            float ct = a + d * 0.125f;
            if (s < 96) { float e = ct - ev; acc += e * e; }
            else {
                float pc = fminf(fmaxf((ct + 1.0f) * 0.5f, 1e-6f), HI);
                acc -= ev * logf(pc) + (1.0f - ev) * log1pf(-pc);
            }
        }
        sh_p64[strip][p] = acc;   // strips 0..47 pure SE, 48..63 pure BCE
    }
    __syncthreads();
    if (tid < 8) {
        float c0 = 0.0f, c1 = 0.0f;
        for (int q = 0; q < 48; ++q)  c0 += sh_p64[q][tid];
        for (int q = 48; q < 64; ++q) c1 += sh_p64[q][tid];
        sh_lcos[64][tid] = c0 / 96.0f;
        sh_lcro[64][tid] = c1 / 32.0f;
    }
    __syncthreads();

    // ---- Phase D: per-p argmin over c (first-min like np.argmin) ----
    if (tid < 8) {
        const int p = tid;
        float best = sh_lcos[0][p] + sh_lcro[0][p];
        int bi = 0;
        for (int c = 1; c < 129; ++c) {
            float v = sh_lcos[c][p] + sh_lcro[c][p];
            if (v < best) { best = v; bi = c; }
        }
        sh_amin[p] = bi;
    }
    __syncthreads();

    // ---- Phase E: 4 smallest rand_vals (stable) -> cnc_indices ----
    if (tid == 0) {
        float rv[8];
        for (int p = 0; p < 8; ++p) rv[p] = rand_vals[t*8 + p];
        const bool tm = t_rand[t] < 0.5f;
        int ci[8];
        bool used[8];
        for (int p = 0; p < 8; ++p) { ci[p] = 64; used[p] = false; }
        for (int jj = 0; jj < 4; ++jj) {
            int bi = -1; float bv = 0.0f;
            for (int p = 0; p < 8; ++p)
                if (!used[p] && (bi < 0 || rv[p] < bv)) { bv = rv[p]; bi = p; }
            used[bi] = true;
            ci[bi] = tm ? sh_amin[bi] : 64;
        }
        for (int p = 0; p < 8; ++p) sh_ci[p] = ci[p];
    }
    __syncthreads();

    // ---- Phase F: gather selected locs + losses; write FLOAT32 out ----
    if (tid < 8) {
        const int p = tid;
        const int idx = sh_ci[p];
        int v;
        if (idx == 64) v = sh_sta[p];
        else {
            int j = (idx < 64) ? idx : (idx - 65);
            int h = j >> 2, k = j & 3;
            int mag = (sh_sta[p] ^ (1 << h)) ^ (sh_rnd[h][k][p] & ((1 << h) - 1));
            v = (idx < 64) ? mag : -mag;
        }
        out[t*8 + p] = (float)v;                  // exact: |v| < 2^16
        sh_selc[p] = sh_lcos[idx][p];
        sh_selr[p] = sh_lcro[idx][p];
    }
    __syncthreads();
    if (tid == 0) {
        float sc = 0.0f, sr = 0.0f, stt = 0.0f;
        for (int p = 0; p < 8; ++p) {
            sc += sh_selc[p];
            sr += sh_selr[p];
            stt += sh_selc[p] + sh_selr[p];
        }
        out[2048 + t]       = sc * 0.125f;        // real_loss_cos
        out[2048 + 256 + t] = sr * 0.125f;        // real_loss_cro
        out[2048 + 512 + t] = stt * 0.125f;       // real_loss_tot
    }
}

extern "C" __attribute__((visibility("default")))
void kernel_launch(void* const* d_in, const int* in_sizes, int n_in,
                   void* d_out, int out_size, void* d_ws, size_t ws_size,
                   hipStream_t stream) {
    const int*   sta = (const int*)d_in[0];
    const int*   pos = (const int*)d_in[1];
    const float* euv = (const float*)d_in[2];
    const float* eun = (const float*)d_in[3];
    // d_in[4] = mask: all ones by construction (lth_cos=96, lth_cro=32 hardcoded)
    const int*   rnd = (const int*)d_in[5];
    const float* rv  = (const float*)d_in[6];
    const float* tr  = (const float*)d_in[7];
    cg_kernel<<<256, NT, 0, stream>>>(sta, pos, euv, eun, rnd, rv, tr, (float*)d_out);
}

// Round 20
// 27.842 us; speedup vs baseline: 1.7652x; 1.0484x over previous
//
#include <hip/hip_runtime.h>

#define NT 1024

// distance magnitude part: (1 - exp/16) * norm, exp = bit_length(xor+1)
__device__ __forceinline__ float dist_mag(int mag, int pos, float norm) {
    int x = (mag ^ pos) + 1;                      // in [1, 65536]
    float s = (float)(32 - __clz(x)) * 0.0625f;   // exp/16, exact
    return (1.0f - s) * norm;                     // one rounding on *norm
}

__global__ __launch_bounds__(NT)
void cg_kernel(const int* __restrict__ sta_loc,
               const int* __restrict__ pos_loc,
               const float* __restrict__ eu_val,
               const float* __restrict__ eu_norm,
               const int* __restrict__ rnd,
               const float* __restrict__ rand_vals,
               const float* __restrict__ t_rand,
               float* __restrict__ out)          // d_out is FLOAT32 (2816 floats)
{
#pragma clang fp contract(off)
    const int t = blockIdx.x;
    const int tid = threadIdx.x;

    __shared__ int   sh_pos[128][8];
    __shared__ float sh_a[128][8];     // (csp_sum - cos)/8
    __shared__ float sh_cos[128][8];   // cos_sta_pos
    __shared__ float sh_euv[128];
    __shared__ float sh_eun[128];
    __shared__ int   sh_sta[8];
    __shared__ int   sh_rnd[16][4][8];
    __shared__ float sh_lcos[129][8];
    __shared__ float sh_lcro[129][8];
    __shared__ float sh_p64[64][8];    // partials for c=64 column
    __shared__ int   sh_amin[8];
    __shared__ int   sh_ci[8];
    __shared__ float sh_selc[8], sh_selr[8];
    // BCE term table: [sign][e-1][s-96 (padded 33)][p] — exact same float
    // expression as inline BCE -> bit-identical accumulation.
    __shared__ float sh_tbl[2][17][33][8];

    // ---- Phase A: stage row t into LDS (inputs are int32) ----
    for (int i = tid; i < 1024; i += NT) ((int*)sh_pos)[i] = pos_loc[t*1024 + i];
    for (int i = tid; i < 512; i += NT)  ((int*)sh_rnd)[i] = rnd[t*512 + i];
    if (tid < 128) { sh_euv[tid] = eu_val[t*128 + tid]; sh_eun[tid] = eu_norm[t*128 + tid]; }
    if (tid >= 128 && tid < 136) sh_sta[tid - 128] = sta_loc[t*8 + (tid - 128)];
    __syncthreads();

    // ---- Phase B: cos_sta_pos, csp_sum, a = (csp - cos)/8 ----
    for (int i = tid; i < 1024; i += NT) {
        int s = i >> 3, p = i & 7;
        sh_cos[s][p] = dist_mag(sh_sta[p], sh_pos[s][p], sh_eun[s]);
    }
    __syncthreads();
    if (tid < 128) {
        float csp = 0.0f;
        for (int p = 0; p < 8; ++p) csp += sh_cos[tid][p];
        for (int p = 0; p < 8; ++p) sh_a[tid][p] = (csp - sh_cos[tid][p]) * 0.125f;
    }
    __syncthreads();

    const float HI = 1.0f - 1e-6f;

    int mag = 0, signSel = 0;   // live across the barrier for lo-threads

    if (tid < 512) {
        // ---- Phase C-SE (lo half): columns c=j (+) and c=j+65 (-) ----
        const int p = tid & 7, j = tid >> 3;
        const int h = j >> 2, k = j & 3;
        mag = (sh_sta[p] ^ (1 << h)) ^ (sh_rnd[h][k][p] & ((1 << h) - 1));
        const float sneg = (mag == 0) ? 1.0f : -1.0f;
        signSel = (mag == 0) ? 0 : 1;

        float accP = 0.0f, accN = 0.0f;
        for (int s = 0; s < 96; ++s) {
            float d  = dist_mag(mag, sh_pos[s][p], sh_eun[s]);
            float a  = sh_a[s][p];
            float ev = sh_euv[s];
            float ctp = a + d * 0.125f;
            float ctn = a + (sneg * d) * 0.125f;
            float e1 = ctp - ev, e2 = ctn - ev;
            accP += e1 * e1;
            accN += e2 * e2;
        }
        sh_lcos[j][p]      = accP / 96.0f;
        sh_lcos[j + 65][p] = accN / 96.0f;
    } else {
        // ---- Phase B2 (hi half): BCE table, 17 entries/thread ----
        for (int i = tid - 512; i < 2 * 17 * 32 * 8; i += 512) {
            int p    = i & 7;
            int sp   = (i >> 3) & 31;
            int r    = i >> 8;              // 0..33
            int sign = (r >= 17) ? 1 : 0;
            int e    = r - sign * 17 + 1;   // 1..17
            int s    = 96 + sp;
            float norm = sh_eun[s];
            float a    = sh_a[s][p];
            float ev   = sh_euv[s];
            float d  = (1.0f - (float)e * 0.0625f) * norm;   // == dist_mag rounding
            float dd = sign ? -d : d;                        // exact sign flip
            float ct = a + dd * 0.125f;
            float pc = fminf(fmaxf((ct + 1.0f) * 0.5f, 1e-6f), HI);
            sh_tbl[sign][e - 1][sp][p] = ev * logf(pc) + (1.0f - ev) * log1pf(-pc);
        }
        // ---- Phase C2 (hi half): c=64 column partials, 2 s-values/thread ----
        const int ht = tid - 512;
        const int p = ht & 7, strip = ht >> 3;   // strip in [0,64)
        float acc = 0.0f;
        for (int ss = 0; ss < 2; ++ss) {
            int s = strip * 2 + ss;
            float d  = sh_cos[s][p];
            float a  = sh_a[s][p];
            float ev = sh_euv[s];
            float ct = a + d * 0.125f;
            if (s < 96) { float e = ct - ev; acc += e * e; }
            else {
                float pc = fminf(fmaxf((ct + 1.0f) * 0.5f, 1e-6f), HI);
                acc -= ev * logf(pc) + (1.0f - ev) * log1pf(-pc);
            }
        }
        sh_p64[strip][p] = acc;   // strips 0..47 pure SE, 48..63 pure BCE
    }
    __syncthreads();

    if (tid < 512) {
        // ---- Phase C-BCE (lo half): table-driven ----
        const int p = tid & 7, j = tid >> 3;
        float bceP = 0.0f, bceN = 0.0f;
        for (int sp = 0; sp < 32; ++sp) {
            int x  = (mag ^ sh_pos[96 + sp][p]) + 1;
            int e0 = 31 - __clz(x);                 // e-1
            bceP -= sh_tbl[0][e0][sp][p];
            bceN -= sh_tbl[signSel][e0][sp][p];
        }
        sh_lcro[j][p]      = bceP / 32.0f;
        sh_lcro[j + 65][p] = bceN / 32.0f;
    }
    __syncthreads();

    // ---- Phase D: c=64 reduction + per-p argmin (same thread: no barrier) ----
    if (tid < 8) {
        float c0 = 0.0f, c1 = 0.0f;
        for (int q = 0; q < 48; ++q)  c0 += sh_p64[q][tid];
        for (int q = 48; q < 64; ++q) c1 += sh_p64[q][tid];
        sh_lcos[64][tid] = c0 / 96.0f;
        sh_lcro[64][tid] = c1 / 32.0f;

        const int p = tid;
        float best = sh_lcos[0][p] + sh_lcro[0][p];
        int bi = 0;
        for (int c = 1; c < 129; ++c) {
            float v = sh_lcos[c][p] + sh_lcro[c][p];
            if (v < best) { best = v; bi = c; }
        }
        sh_amin[p] = bi;
    }
    __syncthreads();

    // ---- Phase E: 4 smallest rand_vals (stable) -> cnc_indices ----
    if (tid == 0) {
        float rv[8];
        for (int p = 0; p < 8; ++p) rv[p] = rand_vals[t*8 + p];
        const bool tm = t_rand[t] < 0.5f;
        int ci[8];
        bool used[8];
        for (int p = 0; p < 8; ++p) { ci[p] = 64; used[p] = false; }
        for (int jj = 0; jj < 4; ++jj) {
            int bi = -1; float bv = 0.0f;
            for (int p = 0; p < 8; ++p)
                if (!used[p] && (bi < 0 || rv[p] < bv)) { bv = rv[p]; bi = p; }
            used[bi] = true;
            ci[bi] = tm ? sh_amin[bi] : 64;
        }
        for (int p = 0; p < 8; ++p) sh_ci[p] = ci[p];
    }
    __syncthreads();

    // ---- Phase F: gather selected locs + losses; write FLOAT32 out ----
    if (tid < 8) {
        const int p = tid;
        const int idx = sh_ci[p];
        int v;
        if (idx == 64) v = sh_sta[p];
        else {
            int j = (idx < 64) ? idx : (idx - 65);
            int h = j >> 2, k = j & 3;
            int m2 = (sh_sta[p] ^ (1 << h)) ^ (sh_rnd[h][k][p] & ((1 << h) - 1));
            v = (idx < 64) ? m2 : -m2;
        }
        out[t*8 + p] = (float)v;                  // exact: |v| < 2^16
        sh_selc[p] = sh_lcos[idx][p];
        sh_selr[p] = sh_lcro[idx][p];
    }
    __syncthreads();
    if (tid == 0) {
        float sc = 0.0f, sr = 0.0f, stt = 0.0f;
        for (int p = 0; p < 8; ++p) {
            sc += sh_selc[p];
            sr += sh_selr[p];
            stt += sh_selc[p] + sh_selr[p];
        }
        out[2048 + t]       = sc * 0.125f;        // real_loss_cos
        out[2048 + 256 + t] = sr * 0.125f;        // real_loss_cro
        out[2048 + 512 + t] = stt * 0.125f;       // real_loss_tot
    }
}

extern "C" __attribute__((visibility("default")))
void kernel_launch(void* const* d_in, const int* in_sizes, int n_in,
                   void* d_out, int out_size, void* d_ws, size_t ws_size,
                   hipStream_t stream) {
    const int*   sta = (const int*)d_in[0];
    const int*   pos = (const int*)d_in[1];
    const float* euv = (const float*)d_in[2];
    const float* eun = (const float*)d_in[3];
    // d_in[4] = mask: all ones by construction (lth_cos=96, lth_cro=32 hardcoded)
    const int*   rnd = (const int*)d_in[5];
    const float* rv  = (const float*)d_in[6];
    const float* tr  = (const float*)d_in[7];
    cg_kernel<<<256, NT, 0, stream>>>(sta, pos, euv, eun, rnd, rv, tr, (float*)d_out);
}